// Round 1
// baseline (167.422 us; speedup 1.0000x reference)
//
#include <hip/hip_runtime.h>
#include <hip/hip_bf16.h>

// LDConv (deformable sampling + (N,1) conv + BN + SiLU) for MI355X.
//
// Round-14 = R13 (proven 116.6 us) + register software-pipelining of the wf
// (weight) loads in k_main:
//  - Theory: each MFMA_HALF issued 8 global loads of wf (L2, ~200-400cy) and
//    consumed them immediately -> 18 exposed L2 round trips per block,
//    phase-locked across the 4 waves by the per-step barrier. MfmaUtil 16%,
//    VALUBusy 29%, HBM 11% => latency-bound, not any roofline.
//  - Fix: Wa (kc0-1) / Wb (kc2-3) register buffers (8 x bf16x8 = 32 VGPR
//    each), each reloaded for step NN+1 right after its step-NN MFMAs
//    consume it -> ~400cy cover (other half's MFMAs + COMBs + barrier).
//  - zwX/zwY copies eliminated: dB0/dB1 reloads moved AFTER their COMBs so
//    COMB reads desc .z/.w directly (-4 VGPR).
//  - Budget: ~124 peak live regs, launch_bounds(256,4) cap 128 KEPT (R12:
//    cap 102 spills; >128 regs halves wave occupancy -> must stay <=128).
//    Fallback if spill observed: drop the Wb prefetch (single-half pipeline).
// Carried: split-set depth gather pipeline (GX/GY serialized, 16 regs),
// XOR-swizzled 16KB dbuf LDS, BN scale folded into wf, fast v_exp/v_rcp
// SiLU, setprio around MFMA, k_offconv (256,6) untouched.

typedef __attribute__((ext_vector_type(8))) short bf16x8;
typedef __attribute__((ext_vector_type(4))) float f32x4;
typedef __attribute__((ext_vector_type(2))) float f32x2;
typedef __attribute__((ext_vector_type(4))) unsigned int u32x4;

#define NHW 6400
#define NPIX 80

__device__ __forceinline__ unsigned short f2bf(float f){
  __hip_bfloat16 h = __float2bfloat16(f);
  unsigned short u; __builtin_memcpy(&u, &h, 2); return u;
}
__device__ __forceinline__ f32x2 bfp2f(unsigned int u){
  union { unsigned int i; float f; } a, b;
  a.i = u << 16; b.i = u & 0xffff0000u;
  f32x2 r; r.x = a.f; r.y = b.f; return r;
}
__device__ __forceinline__ unsigned pk_bf16(float a, float b){
  unsigned r;
  asm("v_cvt_pk_bf16_f32 %0, %1, %2" : "=v"(r) : "v"(a), "v"(b));
  return r;
}
__device__ __forceinline__ void splitbf(float v, unsigned short& hi, unsigned short& lo){
  hi = f2bf(v);
  union { unsigned int i; float f; } h; h.i = (unsigned)hi << 16;
  lo = f2bf(v - h.f);
}
__device__ __forceinline__ float f16u2f(unsigned int u){
  unsigned short s = (unsigned short)u; _Float16 h;
  __builtin_memcpy(&h, &s, 2); return (float)h;
}
__device__ __forceinline__ unsigned short f2f16u(float f){
  _Float16 h = (_Float16)f; unsigned short s;
  __builtin_memcpy(&s, &h, 2); return s;
}
__device__ __forceinline__ float fast_silu(float v){
  float e, r;
  asm("v_exp_f32 %0, %1" : "=v"(e) : "v"(v * -1.44269504088896f)); // exp(-v)
  asm("v_rcp_f32 %0, %1" : "=v"(r) : "v"(1.0f + e));
  return v * r;
}

// ---------------- merged: transpose (blk<800) + weight prep ----------------
__global__ __launch_bounds__(256) void k_pre(const float* __restrict__ x,
                                             const float* __restrict__ w_conv,
                                             const float* __restrict__ w_pconv,
                                             const float* __restrict__ gamma,
                                             const float* __restrict__ beta,
                                             const float* __restrict__ mean,
                                             const float* __restrict__ var,
                                             unsigned short* __restrict__ xt,
                                             unsigned short* __restrict__ xtl,
                                             uint4* __restrict__ wf,
                                             uint4* __restrict__ wpfH,
                                             uint4* __restrict__ wpfL,
                                             float* __restrict__ shift){
  __shared__ unsigned short tileH[64 * 132];
  __shared__ unsigned short tileL[64 * 132];
  int blk = blockIdx.x; int t = threadIdx.x;
  if (blk < 800){
    int b = blk / 100; int pixbase = (blk % 100) * 64;
    int lane = t & 63; int cg = t >> 6;
    for (int ci = 0; ci < 32; ++ci){
      int c = cg * 32 + ci;
      float v = x[(b * 128 + c) * NHW + pixbase + lane];
      unsigned short hi, lo; splitbf(v, hi, lo);
      tileH[lane * 132 + c] = hi;
      tileL[lane * 132 + c] = lo;
    }
    __syncthreads();
    for (int i = 0; i < 8; ++i){
      int slot = t + i * 256; int m = slot >> 5; int c = (slot & 31) * 4;
      uint2 vH = *reinterpret_cast<const uint2*>(&tileH[m * 132 + c]);
      uint2 vL = *reinterpret_cast<const uint2*>(&tileL[m * 132 + c]);
      *reinterpret_cast<uint2*>(xt  + (b * NHW + pixbase + m) * 128 + c) = vH;
      *reinterpret_cast<uint2*>(xtl + (b * NHW + pixbase + m) * 128 + c) = vL;
    }
    return;
  }
  int pblk = blk - 800;
  if (pblk < 144){
    int id = pblk * 256 + t;
    int lane = id & 63, ofrag = (id >> 6) & 15, kc = (id >> 10) & 3, n = id >> 12;
    int o = ofrag * 16 + (lane & 15), cb = kc * 32 + ((lane >> 4) & 3) * 8;
    float sc = gamma[o] * rsqrtf(var[o] + 1e-5f);       // BN scale folded in
    unsigned short h[8];
    for (int j = 0; j < 8; ++j) h[j] = f2bf(w_conv[(o * 128 + cb + j) * 9 + n] * sc);
    uint4 v;
    v.x = (unsigned)h[0] | ((unsigned)h[1] << 16);
    v.y = (unsigned)h[2] | ((unsigned)h[3] << 16);
    v.z = (unsigned)h[4] | ((unsigned)h[5] << 16);
    v.w = (unsigned)h[6] | ((unsigned)h[7] << 16);
    wf[id] = v;
  } else if (pblk < 180){
    int isLo = (pblk >= 162);
    int id = (pblk - (isLo ? 162 : 144)) * 256 + t;
    int lane = id & 63, ofrag = (id >> 6) & 1, kc = (id >> 7) & 3, tap = id >> 9;
    int o = ofrag * 16 + (lane & 15), cb = kc * 32 + ((lane >> 4) & 3) * 8;
    unsigned short h[8];
    for (int j = 0; j < 8; ++j){
      unsigned short hi = 0, lo = 0;
      if (o < 18) splitbf(w_pconv[(o * 128 + cb + j) * 9 + tap], hi, lo);
      h[j] = isLo ? lo : hi;
    }
    uint4 v;
    v.x = (unsigned)h[0] | ((unsigned)h[1] << 16);
    v.y = (unsigned)h[2] | ((unsigned)h[3] << 16);
    v.z = (unsigned)h[4] | ((unsigned)h[5] << 16);
    v.w = (unsigned)h[6] | ((unsigned)h[7] << 16);
    if (isLo) wpfL[id] = v; else wpfH[id] = v;
  } else {
    float sc = gamma[t] * rsqrtf(var[t] + 1e-5f);
    shift[t] = beta[t] - mean[t] * sc;
  }
}

// ---------------- offset conv + descriptor build (32-px tiles) ----------------
__global__ __launch_bounds__(256, 6) void k_offconv(const unsigned short* __restrict__ xt,
                                                    const unsigned short* __restrict__ xtl,
                                                    const uint4* __restrict__ wpfH,
                                                    const uint4* __restrict__ wpfL,
                                                    const float* __restrict__ bpc,
                                                    const float* __restrict__ pn,
                                                    uint4* __restrict__ desc){
  int bid = blockIdx.x;
  int blk = (bid & 7) * 200 + (bid >> 3);          // XCD swizzle (1600 % 8 == 0)
  int b = blk / 200; int pixbase = (blk % 200) * 32;
  int t = threadIdx.x; int lane = t & 63; int wv = t >> 6;
  int og = wv & 1;
  int pf = wv >> 1;
  __shared__ short BtileH[32 * 136];
  __shared__ short BtileL[32 * 136];
  __shared__ float off_lds[32 * 20];

  f32x4 acc = (f32x4){0.f, 0.f, 0.f, 0.f};
  const unsigned short* xbH = xt  + (size_t)b * NHW * 128;
  const unsigned short* xbL = xtl + (size_t)b * NHW * 128;

  int m_i[4], c_i[4], h_i[4], w_i[4];
#pragma unroll
  for (int i = 0; i < 4; ++i){
    int slot = t + i * 256;
    m_i[i] = slot >> 5; c_i[i] = (slot & 31) * 4;
    int p = pixbase + m_i[i];
    h_i[i] = p / NPIX; w_i[i] = p % NPIX;
  }

  uint2 rH[4], rL[4];

#define LOADTAP(DH, DW)                                                        \
  _Pragma("unroll")                                                            \
  for (int i = 0; i < 4; ++i){                                                 \
    int h2 = h_i[i] + (DH), w2 = w_i[i] + (DW);                                \
    uint2 vH; vH.x = 0u; vH.y = 0u;                                            \
    uint2 vL; vL.x = 0u; vL.y = 0u;                                            \
    if ((unsigned)h2 < NPIX && (unsigned)w2 < NPIX){                           \
      int off = (h2 * NPIX + w2) * 128 + c_i[i];                               \
      vH = *reinterpret_cast<const uint2*>(xbH + off);                         \
      vL = *reinterpret_cast<const uint2*>(xbL + off);                         \
    }                                                                          \
    rH[i] = vH; rL[i] = vL;                                                    \
  }

#define WRITETILE()                                                            \
  _Pragma("unroll")                                                            \
  for (int i = 0; i < 4; ++i){                                                 \
    *reinterpret_cast<uint2*>(&BtileH[m_i[i] * 136 + c_i[i]]) = rH[i];         \
    *reinterpret_cast<uint2*>(&BtileL[m_i[i] * 136 + c_i[i]]) = rL[i];         \
  }

  LOADTAP(-1, -1)
  WRITETILE()
  __syncthreads();

#pragma unroll 1
  for (int tap = 0; tap < 9; ++tap){
    if (tap < 8){
      int dh2 = (tap + 1) / 3 - 1, dw2 = (tap + 1) % 3 - 1;
      LOADTAP(dh2, dw2)
    }
#pragma unroll
    for (int kc = 0; kc < 4; ++kc){
      int boff = (pf * 16 + (lane & 15)) * 136 + kc * 32 + ((lane >> 4) & 3) * 8;
      bf16x8 bH = *reinterpret_cast<const bf16x8*>(&BtileH[boff]);
      bf16x8 bL = *reinterpret_cast<const bf16x8*>(&BtileL[boff]);
      int widx = ((tap * 4 + kc) * 2 + og) * 64 + lane;
      bf16x8 aH = *reinterpret_cast<const bf16x8*>(&wpfH[widx]);
      bf16x8 aL = *reinterpret_cast<const bf16x8*>(&wpfL[widx]);
      acc = __builtin_amdgcn_mfma_f32_16x16x32_bf16(aH, bH, acc, 0, 0, 0);
      acc = __builtin_amdgcn_mfma_f32_16x16x32_bf16(aH, bL, acc, 0, 0, 0);
      acc = __builtin_amdgcn_mfma_f32_16x16x32_bf16(aL, bH, acc, 0, 0, 0);
      acc = __builtin_amdgcn_mfma_f32_16x16x32_bf16(aL, bL, acc, 0, 0, 0);
    }
    __syncthreads();
    if (tap < 8){
      WRITETILE()
      __syncthreads();
    }
  }

  int pl = pf * 16 + (lane & 15);
#pragma unroll
  for (int r = 0; r < 4; ++r){
    int o = og * 16 + ((lane >> 4) & 3) * 4 + r;
    if (o < 18) off_lds[pl * 20 + o] = acc[r] + bpc[o];
  }
  __syncthreads();

  for (int item = t; item < 288; item += 256){
    int m = item / 9, n = item % 9;
    int p = pixbase + m; int h = p / NPIX, w = p % NPIX;
    float px = (float)h + pn[n]     + off_lds[m * 20 + n];
    float py = (float)w + pn[9 + n] + off_lds[m * 20 + 9 + n];
    float flx = floorf(px), fly = floorf(py);
    float qltx = fminf(fmaxf(flx, 0.f), 79.f);
    float qrbx = fminf(fmaxf(flx + 1.f, 0.f), 79.f);
    float qlty = fminf(fmaxf(fly, 0.f), 79.f);
    float qrby = fminf(fmaxf(fly + 1.f, 0.f), 79.f);
    float pcx = fminf(fmaxf(px, 0.f), 79.f);
    float pcy = fminf(fmaxf(py, 0.f), 79.f);
    float dxl = 1.f + (qltx - pcx), dxr = 1.f - (qrbx - pcx);
    float dyl = 1.f + (qlty - pcy), dyr = 1.f - (qrby - pcy);
    unsigned ix_l = (unsigned)(int)qltx, ix_r = (unsigned)(int)qrbx;
    unsigned iy_l = (unsigned)(int)qlty, iy_r = (unsigned)(int)qrby;
    uint4 d;
    d.x = (ix_l * NPIX + iy_l) | ((ix_r * NPIX + iy_r) << 16);
    d.y = (ix_l * NPIX + iy_r) | ((ix_r * NPIX + iy_l) << 16);
    d.z = (unsigned)f2f16u(dxl * dyl) | ((unsigned)f2f16u(dxr * dyr) << 16);
    d.w = (unsigned)f2f16u(dxl * dyr) | ((unsigned)f2f16u(dxr * dyl) << 16);
    desc[(size_t)(b * 9 + n) * NHW + p] = d;
  }
#undef LOADTAP
#undef WRITETILE
}

// ---------------- fused: depth gather pipeline + W-prefetched MFMA GEMM + BN + SiLU ----------------
// A_lds: [2 buf][32 rows][256 B], XOR-swizzled: byte_in_row ^= (row&7)<<4.
// Weight pipeline: Wa (kc0-1) / Wb (kc2-3) register buffers, each reloaded
// for step NN+1 immediately after its step-NN MFMAs consume it -> ~400cy
// cover for the wf L2 round trip (was ~80cy -> 18 exposed stalls/block).
// Gather sets stay serialized (GX dies before GY born). Desc .z/.w read
// directly from dB0/dB1 (reloads moved after the COMBs; zw copies removed).
__global__ __launch_bounds__(256, 4) void k_main(const unsigned short* __restrict__ xt,
                                                 const uint4* __restrict__ desc,
                                                 const uint4* __restrict__ wf,
                                                 const float* __restrict__ shift,
                                                 float* __restrict__ out){
  int bid = blockIdx.x;
  int blk = (bid & 7) * 200 + (bid >> 3);          // XCD swizzle (1600 % 8 == 0)
  int b = blk / 200; int pixbase = (blk % 200) * 32;
  int t = threadIdx.x; int lane = t & 63; int ow = t >> 6;
  __shared__ alignas(16) char A_lds[2][32 * 256];  // 16 KB

  const char* xb = (const char*)(xt + (size_t)b * NHW * 128);
  const uint4* descb = desc + (size_t)b * 9 * NHW + pixbase;

  int m0 = t >> 4;            // row 0..15
  int m1 = m0 + 16;           // row 16..31
  int cb = (t & 15) * 16;     // byte col 0..240
  int ls0 = m0 * 256 + (cb ^ ((m0 & 7) << 4));
  int ls1 = m1 * 256 + (cb ^ ((m1 & 7) << 4));

  f32x4 acc[4][2];
#pragma unroll
  for (int of = 0; of < 4; ++of)
#pragma unroll
    for (int pf = 0; pf < 2; ++pf)
      acc[of][pf] = (f32x4){0.f, 0.f, 0.f, 0.f};

  u32x4 GX[4], GY[4];          // serialized liveness (never both live)
  uint4 dB0, dB1;
  bf16x8 Wa[8], Wb[8];         // weight pipeline buffers (32 VGPR each)

#define ISSUE_X()                                                              \
  {                                                                            \
    GX[0] = *reinterpret_cast<const u32x4*>(xb + (dB0.x & 0xffffu) * 256u + (unsigned)cb); \
    GX[1] = *reinterpret_cast<const u32x4*>(xb + (dB0.x >> 16)     * 256u + (unsigned)cb); \
    GX[2] = *reinterpret_cast<const u32x4*>(xb + (dB0.y & 0xffffu) * 256u + (unsigned)cb); \
    GX[3] = *reinterpret_cast<const u32x4*>(xb + (dB0.y >> 16)     * 256u + (unsigned)cb); \
  }

#define ISSUE_Y()                                                              \
  {                                                                            \
    GY[0] = *reinterpret_cast<const u32x4*>(xb + (dB1.x & 0xffffu) * 256u + (unsigned)cb); \
    GY[1] = *reinterpret_cast<const u32x4*>(xb + (dB1.x >> 16)     * 256u + (unsigned)cb); \
    GY[2] = *reinterpret_cast<const u32x4*>(xb + (dB1.y & 0xffffu) * 256u + (unsigned)cb); \
    GY[3] = *reinterpret_cast<const u32x4*>(xb + (dB1.y >> 16)     * 256u + (unsigned)cb); \
  }

#define COMB(G, D, LSO, WB)                                                    \
  {                                                                            \
    float w0 = f16u2f(D.z & 0xffffu), w1 = f16u2f(D.z >> 16);                  \
    float w2 = f16u2f(D.w & 0xffffu), w3 = f16u2f(D.w >> 16);                  \
    u32x4 pk;                                                                  \
    _Pragma("unroll")                                                          \
    for (int j = 0; j < 4; ++j){                                               \
      f32x2 a = w0 * bfp2f(G[0][j]) + w1 * bfp2f(G[1][j])                      \
              + w2 * bfp2f(G[2][j]) + w3 * bfp2f(G[3][j]);                     \
      pk[j] = pk_bf16(a.x, a.y);                                               \
    }                                                                          \
    *reinterpret_cast<u32x4*>((WB) + (LSO)) = pk;                              \
  }

// Load the 8 weight fragments of half {KCA,KCA+1} of step NN into W.
#define WLOAD(W, NN, KCA)                                                      \
  {                                                                            \
    _Pragma("unroll")                                                          \
    for (int j = 0; j < 8; ++j){                                               \
      int kc = (KCA) + (j >> 2); int of = j & 3;                               \
      W[j] = *reinterpret_cast<const bf16x8*>(                                 \
          &wf[((((NN) * 4 + kc) * 16) + ow * 4 + of) * 64 + lane]);            \
    }                                                                          \
  }

#define MFMA_HALF(NN, KCA, KCB, W)                                             \
  {                                                                            \
    const char* ab = &A_lds[(NN) & 1][0];                                      \
    __builtin_amdgcn_s_setprio(1);                                             \
    _Pragma("unroll")                                                          \
    for (int kc = (KCA); kc <= (KCB); ++kc){                                   \
      bf16x8 bfrk[2];                                                          \
      _Pragma("unroll")                                                        \
      for (int pf = 0; pf < 2; ++pf){                                          \
        int row = pf * 16 + (lane & 15);                                       \
        bfrk[pf] = *reinterpret_cast<const bf16x8*>(                           \
            ab + row * 256 + ((kc * 64 + ((lane >> 4) & 3) * 16) ^ ((row & 7) << 4))); \
      }                                                                        \
      _Pragma("unroll")                                                        \
      for (int of = 0; of < 4; ++of){                                          \
        bf16x8 afr = W[(kc - (KCA)) * 4 + of];                                 \
        _Pragma("unroll")                                                      \
        for (int pf = 0; pf < 2; ++pf)                                         \
          acc[of][pf] = __builtin_amdgcn_mfma_f32_16x16x32_bf16(afr, bfrk[pf], acc[of][pf], 0, 0, 0); \
      }                                                                        \
    }                                                                          \
    __builtin_amdgcn_s_setprio(0);                                             \
  }

// STEP(NN): ISSUE_X(data NN+1) | MFMA kc0-1 (Wa) | reload Wa<-step NN+1 |
//           COMB_X (GX dies) | reload dB0<-tap NN+2 | [fence] | ISSUE_Y |
//           MFMA kc2-3 (Wb) | reload Wb<-step NN+1 | COMB_Y | reload dB1 |
//           barrier.  Both W reloads get a full half-step+ of cover; the
//           fences pin load-issue order and keep GX dead before GY is born.
#define STEP(NN)                                                               \
  {                                                                            \
    if ((NN) < 8){ ISSUE_X() }                                                 \
    __builtin_amdgcn_sched_barrier(0);                                         \
    MFMA_HALF(NN, 0, 1, Wa)                                                    \
    if ((NN) < 8){                                                             \
      WLOAD(Wa, (NN) + 1, 0)                                                   \
      __builtin_amdgcn_sched_barrier(0);                                       \
      COMB(GX, dB0, ls0, &A_lds[((NN) + 1) & 1][0])                            \
    }                                                                          \
    if ((NN) < 7){ dB0 = descb[(size_t)((NN) + 2) * NHW + m0]; }               \
    __builtin_amdgcn_sched_barrier(0);                                         \
    if ((NN) < 8){ ISSUE_Y() }                                                 \
    __builtin_amdgcn_sched_barrier(0);                                         \
    MFMA_HALF(NN, 2, 3, Wb)                                                    \
    if ((NN) < 8){                                                             \
      WLOAD(Wb, (NN) + 1, 2)                                                   \
      __builtin_amdgcn_sched_barrier(0);                                       \
      COMB(GY, dB1, ls1, &A_lds[((NN) + 1) & 1][0])                            \
    }                                                                          \
    if ((NN) < 7){ dB1 = descb[(size_t)((NN) + 2) * NHW + m1]; }               \
    __syncthreads();                                                           \
  }

  // prologue: data 0 -> buf0, one gather set live at a time; step-0 weights
  // issued after the gathers so COMB_X's vmcnt wait doesn't drain them.
  dB0 = descb[m0]; dB1 = descb[m1];
  ISSUE_X()
  WLOAD(Wa, 0, 0)
  WLOAD(Wb, 0, 2)
  COMB(GX, dB0, ls0, &A_lds[0][0])
  dB0 = descb[NHW + m0];
  __builtin_amdgcn_sched_barrier(0);
  ISSUE_Y()
  COMB(GY, dB1, ls1, &A_lds[0][0])
  dB1 = descb[NHW + m1];
  __syncthreads();

  STEP(0) STEP(1) STEP(2) STEP(3) STEP(4) STEP(5) STEP(6) STEP(7) STEP(8)

  // epilogue: +shift, fast SiLU, store
#pragma unroll
  for (int of = 0; of < 4; ++of)
#pragma unroll
    for (int pf = 0; pf < 2; ++pf){
      int pix = pixbase + pf * 16 + (lane & 15);
#pragma unroll
      for (int r = 0; r < 4; ++r){
        int o = ow * 64 + of * 16 + ((lane >> 4) & 3) * 4 + r;
        float v = acc[of][pf][r] + shift[o];
        out[(size_t)(b * 256 + o) * NHW + pix] = fast_silu(v);
      }
    }
#undef ISSUE_X
#undef ISSUE_Y
#undef COMB
#undef WLOAD
#undef MFMA_HALF
#undef STEP
}

extern "C" void kernel_launch(void* const* d_in, const int* in_sizes, int n_in,
                              void* d_out, int out_size, void* d_ws, size_t ws_size,
                              hipStream_t stream){
  const float* x       = (const float*)d_in[0];
  const float* w_pconv = (const float*)d_in[1];
  const float* b_pconv = (const float*)d_in[2];
  const float* w_conv  = (const float*)d_in[3];
  const float* gamma   = (const float*)d_in[4];
  const float* beta    = (const float*)d_in[5];
  const float* mean    = (const float*)d_in[6];
  const float* var     = (const float*)d_in[7];
  const float* pn      = (const float*)d_in[8];

  char* ws = (char*)d_ws;
  unsigned short* xt  = (unsigned short*)(ws + 0);           // 13,107,200 B
  unsigned short* xtl = (unsigned short*)(ws + 13107200);    // 13,107,200 B
  uint4* desc         = (uint4*)(ws + 26214400);             //  7,372,800 B
  uint4* wf           = (uint4*)(ws + 33587200);             //    589,824 B
  uint4* wpfH         = (uint4*)(ws + 34177024);             //     73,728 B
  uint4* wpfL         = (uint4*)(ws + 34250752);             //     73,728 B
  float* shift        = (float*)(ws + 34324480);             //      1,024 B
  float* out          = (float*)d_out;

  k_pre<<<981, 256, 0, stream>>>(x, w_conv, w_pconv, gamma, beta, mean, var,
                                 xt, xtl, wf, wpfH, wpfL, shift);
  k_offconv<<<1600, 256, 0, stream>>>(xt, xtl, wpfH, wpfL, b_pconv, pn, desc);
  k_main<<<1600, 256, 0, stream>>>(xt, desc, wf, shift, out);
}

// Round 2
// 114.562 us; speedup vs baseline: 1.4614x; 1.4614x over previous
//
#include <hip/hip_runtime.h>
#include <hip/hip_bf16.h>

// LDConv (deformable sampling + (N,1) conv + BN + SiLU) for MI355X.
//
// Round-15 = R13 (proven 116.6 us) with k_offconv MERGED into k_main
// (k_fused), desc passed through LDS instead of global memory:
//  - R14 post-mortem: Wa/Wb weight pipeline spilled (unified file cap 128
//    at (256,4); WRITE_SIZE 51->235 MB = scratch). Theory was also
//    mis-sized: compiler already batches the 8 wf loads per half, so
//    exposure is ~250cy/half (~6% of block latency), not 30%. Reverted.
//  - This round: desc producer (offset conv) and consumer (gather GEMM)
//    are the SAME (b, 32-px) block in both grids -> merge. Kills the
//    7.37 MB desc write + 7.37 MB read, one full kernel launch + device
//    drain between dependent 1600-block kernels, and moves desc loads
//    off the L2 latency path (LDS broadcast). Phase-1 3x3 taps pre-warm
//    L1/L2 for phase-2 gathers (offsets are small).
//  - LDS union: phase1 Btile/off (20 KB) overlaps phase2 A_lds (16 KB);
//    descL (4.6 KB) persists across both. 24 KB/block, 96 KB @ 4 blk/CU.
//  - Phase code is byte-identical R13 except desc indexing.
// Carried: split-set depth gather pipeline (GX/GY serialized, 16 regs),
// XOR-swizzled 16KB dbuf LDS, BN scale folded into wf, fast v_exp/v_rcp
// SiLU, setprio around MFMA, launch_bounds(256,4) (proven no-spill).

typedef __attribute__((ext_vector_type(8))) short bf16x8;
typedef __attribute__((ext_vector_type(4))) float f32x4;
typedef __attribute__((ext_vector_type(2))) float f32x2;
typedef __attribute__((ext_vector_type(4))) unsigned int u32x4;

#define NHW 6400
#define NPIX 80

__device__ __forceinline__ unsigned short f2bf(float f){
  __hip_bfloat16 h = __float2bfloat16(f);
  unsigned short u; __builtin_memcpy(&u, &h, 2); return u;
}
__device__ __forceinline__ f32x2 bfp2f(unsigned int u){
  union { unsigned int i; float f; } a, b;
  a.i = u << 16; b.i = u & 0xffff0000u;
  f32x2 r; r.x = a.f; r.y = b.f; return r;
}
__device__ __forceinline__ unsigned pk_bf16(float a, float b){
  unsigned r;
  asm("v_cvt_pk_bf16_f32 %0, %1, %2" : "=v"(r) : "v"(a), "v"(b));
  return r;
}
__device__ __forceinline__ void splitbf(float v, unsigned short& hi, unsigned short& lo){
  hi = f2bf(v);
  union { unsigned int i; float f; } h; h.i = (unsigned)hi << 16;
  lo = f2bf(v - h.f);
}
__device__ __forceinline__ float f16u2f(unsigned int u){
  unsigned short s = (unsigned short)u; _Float16 h;
  __builtin_memcpy(&h, &s, 2); return (float)h;
}
__device__ __forceinline__ unsigned short f2f16u(float f){
  _Float16 h = (_Float16)f; unsigned short s;
  __builtin_memcpy(&s, &h, 2); return s;
}
__device__ __forceinline__ float fast_silu(float v){
  float e, r;
  asm("v_exp_f32 %0, %1" : "=v"(e) : "v"(v * -1.44269504088896f)); // exp(-v)
  asm("v_rcp_f32 %0, %1" : "=v"(r) : "v"(1.0f + e));
  return v * r;
}

// ---------------- merged: transpose (blk<800) + weight prep ----------------
__global__ __launch_bounds__(256) void k_pre(const float* __restrict__ x,
                                             const float* __restrict__ w_conv,
                                             const float* __restrict__ w_pconv,
                                             const float* __restrict__ gamma,
                                             const float* __restrict__ beta,
                                             const float* __restrict__ mean,
                                             const float* __restrict__ var,
                                             unsigned short* __restrict__ xt,
                                             unsigned short* __restrict__ xtl,
                                             uint4* __restrict__ wf,
                                             uint4* __restrict__ wpfH,
                                             uint4* __restrict__ wpfL,
                                             float* __restrict__ shift){
  __shared__ unsigned short tileH[64 * 132];
  __shared__ unsigned short tileL[64 * 132];
  int blk = blockIdx.x; int t = threadIdx.x;
  if (blk < 800){
    int b = blk / 100; int pixbase = (blk % 100) * 64;
    int lane = t & 63; int cg = t >> 6;
    for (int ci = 0; ci < 32; ++ci){
      int c = cg * 32 + ci;
      float v = x[(b * 128 + c) * NHW + pixbase + lane];
      unsigned short hi, lo; splitbf(v, hi, lo);
      tileH[lane * 132 + c] = hi;
      tileL[lane * 132 + c] = lo;
    }
    __syncthreads();
    for (int i = 0; i < 8; ++i){
      int slot = t + i * 256; int m = slot >> 5; int c = (slot & 31) * 4;
      uint2 vH = *reinterpret_cast<const uint2*>(&tileH[m * 132 + c]);
      uint2 vL = *reinterpret_cast<const uint2*>(&tileL[m * 132 + c]);
      *reinterpret_cast<uint2*>(xt  + (b * NHW + pixbase + m) * 128 + c) = vH;
      *reinterpret_cast<uint2*>(xtl + (b * NHW + pixbase + m) * 128 + c) = vL;
    }
    return;
  }
  int pblk = blk - 800;
  if (pblk < 144){
    int id = pblk * 256 + t;
    int lane = id & 63, ofrag = (id >> 6) & 15, kc = (id >> 10) & 3, n = id >> 12;
    int o = ofrag * 16 + (lane & 15), cb = kc * 32 + ((lane >> 4) & 3) * 8;
    float sc = gamma[o] * rsqrtf(var[o] + 1e-5f);       // BN scale folded in
    unsigned short h[8];
    for (int j = 0; j < 8; ++j) h[j] = f2bf(w_conv[(o * 128 + cb + j) * 9 + n] * sc);
    uint4 v;
    v.x = (unsigned)h[0] | ((unsigned)h[1] << 16);
    v.y = (unsigned)h[2] | ((unsigned)h[3] << 16);
    v.z = (unsigned)h[4] | ((unsigned)h[5] << 16);
    v.w = (unsigned)h[6] | ((unsigned)h[7] << 16);
    wf[id] = v;
  } else if (pblk < 180){
    int isLo = (pblk >= 162);
    int id = (pblk - (isLo ? 162 : 144)) * 256 + t;
    int lane = id & 63, ofrag = (id >> 6) & 1, kc = (id >> 7) & 3, tap = id >> 9;
    int o = ofrag * 16 + (lane & 15), cb = kc * 32 + ((lane >> 4) & 3) * 8;
    unsigned short h[8];
    for (int j = 0; j < 8; ++j){
      unsigned short hi = 0, lo = 0;
      if (o < 18) splitbf(w_pconv[(o * 128 + cb + j) * 9 + tap], hi, lo);
      h[j] = isLo ? lo : hi;
    }
    uint4 v;
    v.x = (unsigned)h[0] | ((unsigned)h[1] << 16);
    v.y = (unsigned)h[2] | ((unsigned)h[3] << 16);
    v.z = (unsigned)h[4] | ((unsigned)h[5] << 16);
    v.w = (unsigned)h[6] | ((unsigned)h[7] << 16);
    if (isLo) wpfL[id] = v; else wpfH[id] = v;
  } else {
    float sc = gamma[t] * rsqrtf(var[t] + 1e-5f);
    shift[t] = beta[t] - mean[t] * sc;
  }
}

// ---------------- fused: offset conv -> descL (LDS) -> gather GEMM + BN + SiLU ----------------
// Phase 1 (== k_offconv body): 3x3 offset conv via dbl-bf16 MFMA, descriptor
// build into descL[9*32] in LDS (global desc round-trip eliminated).
// Phase 2 (== k_main body): depth gather pipeline + MFMA GEMM.
// LDS map (24576 B): [0,17408) BtileH/L  | [17408,19968) off_lds
//                    [0,16384)  A_lds[2] (phase 2, after barrier)
//                    [19968,24576) descL (persists across phases)
__global__ __launch_bounds__(256, 4) void k_fused(const unsigned short* __restrict__ xt,
                                                  const unsigned short* __restrict__ xtl,
                                                  const uint4* __restrict__ wpfH,
                                                  const uint4* __restrict__ wpfL,
                                                  const float* __restrict__ bpc,
                                                  const float* __restrict__ pn,
                                                  const uint4* __restrict__ wf,
                                                  const float* __restrict__ shift,
                                                  float* __restrict__ out){
  int bid = blockIdx.x;
  int blk = (bid & 7) * 200 + (bid >> 3);          // XCD swizzle (1600 % 8 == 0)
  int b = blk / 200; int pixbase = (blk % 200) * 32;
  int t = threadIdx.x; int lane = t & 63;

  __shared__ alignas(16) char smem[24576];
  short* BtileH  = (short*)(smem);                 // 32*136*2 = 8704 B
  short* BtileL  = (short*)(smem + 8704);          // 8704 B
  float* off_lds = (float*)(smem + 17408);         // 32*20*4 = 2560 B
  uint4* descL   = (uint4*)(smem + 19968);         // 9*32*16 = 4608 B

  // ======================= phase 1: offset conv =======================
  {
    int wv = t >> 6; int og = wv & 1; int pf = wv >> 1;
    f32x4 acc = (f32x4){0.f, 0.f, 0.f, 0.f};
    const unsigned short* xbH = xt  + (size_t)b * NHW * 128;
    const unsigned short* xbL = xtl + (size_t)b * NHW * 128;

    int m_i[4], c_i[4], h_i[4], w_i[4];
#pragma unroll
    for (int i = 0; i < 4; ++i){
      int slot = t + i * 256;
      m_i[i] = slot >> 5; c_i[i] = (slot & 31) * 4;
      int p = pixbase + m_i[i];
      h_i[i] = p / NPIX; w_i[i] = p % NPIX;
    }

    uint2 rH[4], rL[4];

#define LOADTAP(DH, DW)                                                        \
  _Pragma("unroll")                                                            \
  for (int i = 0; i < 4; ++i){                                                 \
    int h2 = h_i[i] + (DH), w2 = w_i[i] + (DW);                                \
    uint2 vH; vH.x = 0u; vH.y = 0u;                                            \
    uint2 vL; vL.x = 0u; vL.y = 0u;                                            \
    if ((unsigned)h2 < NPIX && (unsigned)w2 < NPIX){                           \
      int off = (h2 * NPIX + w2) * 128 + c_i[i];                               \
      vH = *reinterpret_cast<const uint2*>(xbH + off);                         \
      vL = *reinterpret_cast<const uint2*>(xbL + off);                         \
    }                                                                          \
    rH[i] = vH; rL[i] = vL;                                                    \
  }

#define WRITETILE()                                                            \
  _Pragma("unroll")                                                            \
  for (int i = 0; i < 4; ++i){                                                 \
    *reinterpret_cast<uint2*>(&BtileH[m_i[i] * 136 + c_i[i]]) = rH[i];         \
    *reinterpret_cast<uint2*>(&BtileL[m_i[i] * 136 + c_i[i]]) = rL[i];         \
  }

    LOADTAP(-1, -1)
    WRITETILE()
    __syncthreads();

#pragma unroll 1
    for (int tap = 0; tap < 9; ++tap){
      if (tap < 8){
        int dh2 = (tap + 1) / 3 - 1, dw2 = (tap + 1) % 3 - 1;
        LOADTAP(dh2, dw2)
      }
#pragma unroll
      for (int kc = 0; kc < 4; ++kc){
        int boff = (pf * 16 + (lane & 15)) * 136 + kc * 32 + ((lane >> 4) & 3) * 8;
        bf16x8 bH = *reinterpret_cast<const bf16x8*>(&BtileH[boff]);
        bf16x8 bL = *reinterpret_cast<const bf16x8*>(&BtileL[boff]);
        int widx = ((tap * 4 + kc) * 2 + og) * 64 + lane;
        bf16x8 aH = *reinterpret_cast<const bf16x8*>(&wpfH[widx]);
        bf16x8 aL = *reinterpret_cast<const bf16x8*>(&wpfL[widx]);
        acc = __builtin_amdgcn_mfma_f32_16x16x32_bf16(aH, bH, acc, 0, 0, 0);
        acc = __builtin_amdgcn_mfma_f32_16x16x32_bf16(aH, bL, acc, 0, 0, 0);
        acc = __builtin_amdgcn_mfma_f32_16x16x32_bf16(aL, bH, acc, 0, 0, 0);
        acc = __builtin_amdgcn_mfma_f32_16x16x32_bf16(aL, bL, acc, 0, 0, 0);
      }
      __syncthreads();
      if (tap < 8){
        WRITETILE()
        __syncthreads();
      }
    }

    int pl = pf * 16 + (lane & 15);
#pragma unroll
    for (int r = 0; r < 4; ++r){
      int o = og * 16 + ((lane >> 4) & 3) * 4 + r;
      if (o < 18) off_lds[pl * 20 + o] = acc[r] + bpc[o];
    }
    __syncthreads();

    for (int item = t; item < 288; item += 256){
      int m = item / 9, n = item % 9;
      int p = pixbase + m; int h = p / NPIX, w = p % NPIX;
      float px = (float)h + pn[n]     + off_lds[m * 20 + n];
      float py = (float)w + pn[9 + n] + off_lds[m * 20 + 9 + n];
      float flx = floorf(px), fly = floorf(py);
      float qltx = fminf(fmaxf(flx, 0.f), 79.f);
      float qrbx = fminf(fmaxf(flx + 1.f, 0.f), 79.f);
      float qlty = fminf(fmaxf(fly, 0.f), 79.f);
      float qrby = fminf(fmaxf(fly + 1.f, 0.f), 79.f);
      float pcx = fminf(fmaxf(px, 0.f), 79.f);
      float pcy = fminf(fmaxf(py, 0.f), 79.f);
      float dxl = 1.f + (qltx - pcx), dxr = 1.f - (qrbx - pcx);
      float dyl = 1.f + (qlty - pcy), dyr = 1.f - (qrby - pcy);
      unsigned ix_l = (unsigned)(int)qltx, ix_r = (unsigned)(int)qrbx;
      unsigned iy_l = (unsigned)(int)qlty, iy_r = (unsigned)(int)qrby;
      uint4 d;
      d.x = (ix_l * NPIX + iy_l) | ((ix_r * NPIX + iy_r) << 16);
      d.y = (ix_l * NPIX + iy_r) | ((ix_r * NPIX + iy_l) << 16);
      d.z = (unsigned)f2f16u(dxl * dyl) | ((unsigned)f2f16u(dxr * dyr) << 16);
      d.w = (unsigned)f2f16u(dxl * dyr) | ((unsigned)f2f16u(dxr * dyl) << 16);
      descL[n * 32 + m] = d;
    }
#undef LOADTAP
#undef WRITETILE
  }
  __syncthreads();                 // descL visible; Btile region dead
  __builtin_amdgcn_sched_barrier(0);

  // ======================= phase 2: gather GEMM =======================
  {
    int ow = t >> 6;
    char* A_lds0 = smem;                 // A_lds[buf] = smem + buf*8192
    const char* xb = (const char*)(xt + (size_t)b * NHW * 128);

    int m0 = t >> 4;            // row 0..15
    int m1 = m0 + 16;           // row 16..31
    int cb = (t & 15) * 16;     // byte col 0..240
    int ls0 = m0 * 256 + (cb ^ ((m0 & 7) << 4));
    int ls1 = m1 * 256 + (cb ^ ((m1 & 7) << 4));

    f32x4 acc[4][2];
#pragma unroll
    for (int of = 0; of < 4; ++of)
#pragma unroll
      for (int pf = 0; pf < 2; ++pf)
        acc[of][pf] = (f32x4){0.f, 0.f, 0.f, 0.f};

    u32x4 GX[4], GY[4];          // serialized liveness (never both live)
    uint2 zwX, zwY;
    uint4 dB0, dB1;

#define DLD(N, M) descL[(N) * 32 + (M)]

#define ISSUE_X()                                                              \
  {                                                                            \
    zwX.x = dB0.z; zwX.y = dB0.w;                                              \
    GX[0] = *reinterpret_cast<const u32x4*>(xb + (dB0.x & 0xffffu) * 256u + (unsigned)cb); \
    GX[1] = *reinterpret_cast<const u32x4*>(xb + (dB0.x >> 16)     * 256u + (unsigned)cb); \
    GX[2] = *reinterpret_cast<const u32x4*>(xb + (dB0.y & 0xffffu) * 256u + (unsigned)cb); \
    GX[3] = *reinterpret_cast<const u32x4*>(xb + (dB0.y >> 16)     * 256u + (unsigned)cb); \
  }

#define ISSUE_Y()                                                              \
  {                                                                            \
    zwY.x = dB1.z; zwY.y = dB1.w;                                              \
    GY[0] = *reinterpret_cast<const u32x4*>(xb + (dB1.x & 0xffffu) * 256u + (unsigned)cb); \
    GY[1] = *reinterpret_cast<const u32x4*>(xb + (dB1.x >> 16)     * 256u + (unsigned)cb); \
    GY[2] = *reinterpret_cast<const u32x4*>(xb + (dB1.y & 0xffffu) * 256u + (unsigned)cb); \
    GY[3] = *reinterpret_cast<const u32x4*>(xb + (dB1.y >> 16)     * 256u + (unsigned)cb); \
  }

#define COMB(G, ZW, LSO, WB)                                                   \
  {                                                                            \
    float w0 = f16u2f(ZW.x & 0xffffu), w1 = f16u2f(ZW.x >> 16);                \
    float w2 = f16u2f(ZW.y & 0xffffu), w3 = f16u2f(ZW.y >> 16);                \
    u32x4 pk;                                                                  \
    _Pragma("unroll")                                                          \
    for (int j = 0; j < 4; ++j){                                               \
      f32x2 a = w0 * bfp2f(G[0][j]) + w1 * bfp2f(G[1][j])                      \
              + w2 * bfp2f(G[2][j]) + w3 * bfp2f(G[3][j]);                     \
      pk[j] = pk_bf16(a.x, a.y);                                               \
    }                                                                          \
    *reinterpret_cast<u32x4*>((WB) + (LSO)) = pk;                              \
  }

#define MFMA_HALF(NN, KCA, KCB)                                                \
  {                                                                            \
    const char* ab = A_lds0 + ((NN) & 1) * 8192;                               \
    __builtin_amdgcn_s_setprio(1);                                             \
    _Pragma("unroll")                                                          \
    for (int kc = (KCA); kc <= (KCB); ++kc){                                   \
      bf16x8 bfrk[2];                                                          \
      _Pragma("unroll")                                                        \
      for (int pf = 0; pf < 2; ++pf){                                          \
        int row = pf * 16 + (lane & 15);                                       \
        bfrk[pf] = *reinterpret_cast<const bf16x8*>(                           \
            ab + row * 256 + ((kc * 64 + ((lane >> 4) & 3) * 16) ^ ((row & 7) << 4))); \
      }                                                                        \
      _Pragma("unroll")                                                        \
      for (int of = 0; of < 4; ++of){                                          \
        bf16x8 afr = *reinterpret_cast<const bf16x8*>(                         \
            &wf[((((NN) * 4 + kc) * 16) + ow * 4 + of) * 64 + lane]);          \
        _Pragma("unroll")                                                      \
        for (int pf = 0; pf < 2; ++pf)                                         \
          acc[of][pf] = __builtin_amdgcn_mfma_f32_16x16x32_bf16(afr, bfrk[pf], acc[of][pf], 0, 0, 0); \
      }                                                                        \
    }                                                                          \
    __builtin_amdgcn_s_setprio(0);                                             \
  }

// STEP(NN): issue X(data NN+1) | descL0(NN+2) | MFMA kc0-1 | COMB_X (GX dies)
//           | [sched fence] | issue Y(NN+1) | descL1(NN+2) | MFMA kc2-3
//           | COMB_Y | barrier.
#define STEP(NN)                                                               \
  {                                                                            \
    if ((NN) < 8){ ISSUE_X() }                                                 \
    if ((NN) < 7){ dB0 = DLD((NN) + 2, m0); }                                  \
    MFMA_HALF(NN, 0, 1)                                                        \
    if ((NN) < 8){                                                             \
      COMB(GX, zwX, ls0, A_lds0 + (((NN) + 1) & 1) * 8192)                     \
      __builtin_amdgcn_sched_barrier(0);                                       \
      ISSUE_Y()                                                                \
    }                                                                          \
    if ((NN) < 7){ dB1 = DLD((NN) + 2, m1); }                                  \
    MFMA_HALF(NN, 2, 3)                                                        \
    if ((NN) < 8){                                                             \
      COMB(GY, zwY, ls1, A_lds0 + (((NN) + 1) & 1) * 8192)                     \
    }                                                                          \
    __syncthreads();                                                           \
  }

    // prologue: data 0 -> buf0, one gather set live at a time
    dB0 = DLD(0, m0); dB1 = DLD(0, m1);
    ISSUE_X()
    COMB(GX, zwX, ls0, A_lds0)
    __builtin_amdgcn_sched_barrier(0);
    ISSUE_Y()
    COMB(GY, zwY, ls1, A_lds0)
    dB0 = DLD(1, m0); dB1 = DLD(1, m1);
    __syncthreads();

    STEP(0) STEP(1) STEP(2) STEP(3) STEP(4) STEP(5) STEP(6) STEP(7) STEP(8)

    // epilogue: +shift, fast SiLU, store
#pragma unroll
    for (int of = 0; of < 4; ++of)
#pragma unroll
      for (int pf = 0; pf < 2; ++pf){
        int pix = pixbase + pf * 16 + (lane & 15);
#pragma unroll
        for (int r = 0; r < 4; ++r){
          int o = ow * 64 + of * 16 + ((lane >> 4) & 3) * 4 + r;
          float v = acc[of][pf][r] + shift[o];
          out[(size_t)(b * 256 + o) * NHW + pix] = fast_silu(v);
        }
      }
#undef DLD
#undef ISSUE_X
#undef ISSUE_Y
#undef COMB
#undef MFMA_HALF
#undef STEP
  }
}

extern "C" void kernel_launch(void* const* d_in, const int* in_sizes, int n_in,
                              void* d_out, int out_size, void* d_ws, size_t ws_size,
                              hipStream_t stream){
  const float* x       = (const float*)d_in[0];
  const float* w_pconv = (const float*)d_in[1];
  const float* b_pconv = (const float*)d_in[2];
  const float* w_conv  = (const float*)d_in[3];
  const float* gamma   = (const float*)d_in[4];
  const float* beta    = (const float*)d_in[5];
  const float* mean    = (const float*)d_in[6];
  const float* var     = (const float*)d_in[7];
  const float* pn      = (const float*)d_in[8];

  char* ws = (char*)d_ws;
  unsigned short* xt  = (unsigned short*)(ws + 0);           // 13,107,200 B
  unsigned short* xtl = (unsigned short*)(ws + 13107200);    // 13,107,200 B
  // (desc region [26214400, 33587200) now unused — kept for layout stability)
  uint4* wf           = (uint4*)(ws + 33587200);             //    589,824 B
  uint4* wpfH         = (uint4*)(ws + 34177024);             //     73,728 B
  uint4* wpfL         = (uint4*)(ws + 34250752);             //     73,728 B
  float* shift        = (float*)(ws + 34324480);             //      1,024 B
  float* out          = (float*)d_out;

  k_pre<<<981, 256, 0, stream>>>(x, w_conv, w_pconv, gamma, beta, mean, var,
                                 xt, xtl, wf, wpfH, wpfL, shift);
  k_fused<<<1600, 256, 0, stream>>>(xt, xtl, wpfH, wpfL, b_pconv, pn, wf, shift, out);
}